// Round 1
// baseline (2063.337 us; speedup 1.0000x reference)
//
#include <hip/hip_runtime.h>

#define N_NODES 50000
#define N_EDGES 800000
#define N_ELEM  10
#define F_IN    128
#define F_OUT   128
#define NQ      100            // N_ELEM * N_ELEM
#define C_STRIDE 104           // padded, 416 B = 16B-aligned rows
#define EDGES_PER_WAVE 8
#define NGROUPS (N_EDGES / EDGES_PER_WAVE)   // 100000 exactly, no tail

// LDS layout (floats):
//   Wd  [100][128]   offset 0      (12800 f)  = diag(weights1)
//   W2s [128][128]   offset 12800  (16384 f)
//   cb  [4][8][104]  offset 29184  ( 3328 f)  per-wave outer products
//   Mb  [4][8][128]  offset 32512  ( 4096 f)  per-wave modulated t
// total 36608 floats = 146432 B  (< 160 KiB LDS)

__global__ __launch_bounds__(256, 1)
void tpwb_kernel(const float* __restrict__ na,
                 const float* __restrict__ ef,
                 const void*  __restrict__ eidx,
                 const float* __restrict__ w1,
                 const float* __restrict__ w2,
                 float* __restrict__ outp)
{
    extern __shared__ float smem[];
    float* Wd  = smem;            // [100][128]
    float* W2s = smem + 12800;    // [128][128]
    const int tid  = threadIdx.x;
    const int lane = tid & 63;
    const int w    = tid >> 6;
    float* cw = smem + 29184 + w * (EDGES_PER_WAVE * C_STRIDE);
    float* Mw = smem + 32512 + w * (EDGES_PER_WAVE * F_IN);

    // ---- detect edge_index dtype: int64 -> all odd dwords of first 16 entries are 0
    const int* p32 = (const int*)eidx;
    bool is64 = true;
    #pragma unroll
    for (int k = 1; k < 32; k += 2) { if (p32[k] != 0) is64 = false; }
    const long long* p64 = (const long long*)eidx;

    // ---- stage weights into LDS (once per persistent block)
    for (int i = tid; i < NQ * F_IN; i += 256) {
        int q = i >> 7, n = i & 127;
        Wd[i] = w1[q * (F_IN * F_IN) + n * (F_IN + 1)];   // weights1[i,j,n,n]
    }
    for (int i = tid; i < (F_IN * F_OUT) / 4; i += 256) {
        ((float4*)W2s)[i] = ((const float4*)w2)[i];
    }
    __syncthreads();

    const int e   = lane >> 3;      // 0..7 : edge within the wave's group
    const int sub = lane & 7;       // 0..7 : worker within edge
    const int gw     = blockIdx.x * 4 + w;
    const int stride = gridDim.x * 4;

    for (int g = gw; g < NGROUPS; g += stride) {
        const long base = (long)g * EDGES_PER_WAVE;

        // ---- gather node attrs, build outer products c[e][q]
        int snd, rcv;
        if (is64) {
            snd = (int)p64[base + e];
            rcv = (int)p64[N_EDGES + base + e];
        } else {
            snd = p32[base + e];
            rcv = p32[N_EDGES + base + e];
        }
        const float* nas = na + snd * N_ELEM;
        const float* nar = na + rcv * N_ELEM;
        #pragma unroll
        for (int rep = 0; rep < 13; ++rep) {
            int q = rep * 8 + sub;
            if (q < NQ) {
                int i10 = (q * 205) >> 11;     // q / 10 for q<1024
                int j10 = q - i10 * 10;
                cw[e * C_STRIDE + q] = nas[i10] * nar[j10];
            }
        }

        // prefetch edge feats (this lane's float2 of each of the 8 edges)
        float2 efv[8];
        #pragma unroll
        for (int ee = 0; ee < 8; ++ee)
            efv[ee] = *(const float2*)&ef[(base + ee) * F_IN + 2 * lane];

        asm volatile("s_waitcnt lgkmcnt(0)" ::: "memory");  // c visible wave-wide

        // ---- phase A: t[e, 2*lane .. 2*lane+1] = sum_q c[e,q] * Wd[q,n]
        float tx[8], ty[8];
        #pragma unroll
        for (int ee = 0; ee < 8; ++ee) { tx[ee] = 0.f; ty[ee] = 0.f; }
        for (int q0 = 0; q0 < NQ; q0 += 4) {
            float2 wd0 = *(const float2*)&Wd[(q0 + 0) * F_IN + 2 * lane];
            float2 wd1 = *(const float2*)&Wd[(q0 + 1) * F_IN + 2 * lane];
            float2 wd2 = *(const float2*)&Wd[(q0 + 2) * F_IN + 2 * lane];
            float2 wd3 = *(const float2*)&Wd[(q0 + 3) * F_IN + 2 * lane];
            #pragma unroll
            for (int ee = 0; ee < 8; ++ee) {
                float4 cc = *(const float4*)&cw[ee * C_STRIDE + q0];
                tx[ee] = fmaf(cc.x, wd0.x, tx[ee]);
                ty[ee] = fmaf(cc.x, wd0.y, ty[ee]);
                tx[ee] = fmaf(cc.y, wd1.x, tx[ee]);
                ty[ee] = fmaf(cc.y, wd1.y, ty[ee]);
                tx[ee] = fmaf(cc.z, wd2.x, tx[ee]);
                ty[ee] = fmaf(cc.z, wd2.y, ty[ee]);
                tx[ee] = fmaf(cc.w, wd3.x, tx[ee]);
                ty[ee] = fmaf(cc.w, wd3.y, ty[ee]);
            }
        }

        // ---- modulate by edge feats, transpose through LDS
        #pragma unroll
        for (int ee = 0; ee < 8; ++ee) {
            float2 m2;
            m2.x = tx[ee] * efv[ee].x;
            m2.y = ty[ee] * efv[ee].y;
            *(float2*)&Mw[ee * F_IN + 2 * lane] = m2;
        }
        asm volatile("s_waitcnt lgkmcnt(0)" ::: "memory");  // M visible wave-wide

        // ---- phase B: out[e,k] = sum_n M[e,n] * W2[n,k]
        float ox[8], oy[8];
        #pragma unroll
        for (int ee = 0; ee < 8; ++ee) { ox[ee] = 0.f; oy[ee] = 0.f; }
        for (int n0 = 0; n0 < F_IN; n0 += 4) {
            float2 u0 = *(const float2*)&W2s[(n0 + 0) * F_OUT + 2 * lane];
            float2 u1 = *(const float2*)&W2s[(n0 + 1) * F_OUT + 2 * lane];
            float2 u2 = *(const float2*)&W2s[(n0 + 2) * F_OUT + 2 * lane];
            float2 u3 = *(const float2*)&W2s[(n0 + 3) * F_OUT + 2 * lane];
            #pragma unroll
            for (int ee = 0; ee < 8; ++ee) {
                float4 mm = *(const float4*)&Mw[ee * F_IN + n0];
                ox[ee] = fmaf(mm.x, u0.x, ox[ee]);
                oy[ee] = fmaf(mm.x, u0.y, oy[ee]);
                ox[ee] = fmaf(mm.y, u1.x, ox[ee]);
                oy[ee] = fmaf(mm.y, u1.y, oy[ee]);
                ox[ee] = fmaf(mm.z, u2.x, ox[ee]);
                oy[ee] = fmaf(mm.z, u2.y, oy[ee]);
                ox[ee] = fmaf(mm.w, u3.x, ox[ee]);
                oy[ee] = fmaf(mm.w, u3.y, oy[ee]);
            }
        }

        #pragma unroll
        for (int ee = 0; ee < 8; ++ee) {
            float2 o2; o2.x = ox[ee]; o2.y = oy[ee];
            *(float2*)&outp[(base + ee) * F_OUT + 2 * lane] = o2;
        }
        // drain before next iteration reuses cw/Mw
        asm volatile("s_waitcnt lgkmcnt(0)" ::: "memory");
    }
}

extern "C" void kernel_launch(void* const* d_in, const int* in_sizes, int n_in,
                              void* d_out, int out_size, void* d_ws, size_t ws_size,
                              hipStream_t stream) {
    const float* na   = (const float*)d_in[0];   // node_attrs  [50000,10]
    const float* ef   = (const float*)d_in[1];   // edge_feats  [800000,128]
    const void*  eidx = d_in[2];                 // edge_index  [2,800000] int32/int64
    const float* w1   = (const float*)d_in[3];   // weights1    [10,10,128,128]
    const float* w2   = (const float*)d_in[4];   // weights2    [128,128]
    float* outp = (float*)d_out;                 // [800000,128] fp32

    const size_t smem = 36608 * sizeof(float);   // 146432 B
    tpwb_kernel<<<dim3(256), dim3(256), smem, stream>>>(na, ef, eidx, w1, w2, outp);
}